// Round 11
// baseline (243.019 us; speedup 1.0000x reference)
//
#include <hip/hip_runtime.h>
#include <hip/hip_bf16.h>

// Problem constants
#define BB 8
#define NN 1024
#define CC 544      // J*F = 17*32
#define JJ 17
#define FF 32
#define HH 8
#define HD 68
#define BN 8192     // B*N
#define KD 544      // GEMM K dim (=C)
#define NCQ 1632    // 3*C
#define NCQP 1664   // padded to 13*128
#define NCPP 640    // proj out padded to 5*128
#define HDP 96      // head dim padded for QK (3x K=32)
#define AQR 64      // q-rows per attention block (2 waves x 2 groups x 16)

using f32x4  = __attribute__((ext_vector_type(4))) float;
using bf16x8 = __attribute__((ext_vector_type(8))) short;

__device__ __forceinline__ void gld_lds16(const void* g, void* l) {
  __builtin_amdgcn_global_load_lds(
      (const __attribute__((address_space(1))) void*)g,
      (__attribute__((address_space(3))) void*)l, 16, 0, 0);
}

// ---------------------------------------------------------------- K0: weights -> bf16 (padded) + zero Qp/Kp pad cols
__global__ __launch_bounds__(256) void wconv(const float* __restrict__ qkv_w,
                                             const float* __restrict__ proj_w,
                                             __hip_bfloat16* __restrict__ qw,
                                             __hip_bfloat16* __restrict__ pw,
                                             char* __restrict__ qkp) {
  int idx = blockIdx.x * 256 + threadIdx.x;
  const int t1 = NCQP * KD;            // 905216
  const int t2 = t1 + NCPP * KD;       // 1253376
  if (idx < t1) {
    int r = idx / KD;
    qw[idx] = __float2bfloat16(r < NCQ ? qkv_w[idx] : 0.f);
  } else if (idx < t2) {
    int k = idx - t1;
    int r = k / KD;
    pw[k] = __float2bfloat16(r < CC ? proj_w[k] : 0.f);
  } else {
    // zero pad cols 68..95 of Qp||Kp: 131072 rows x 7 qwords (56B at byte 136)
    int k = idx - t2;
    if (k < 131072 * 7) {
      int row = k / 7, i = k - row * 7;
      *(unsigned long long*)(qkp + (size_t)row * 192 + 136 + i * 8) = 0ull;
    }
  }
}

// ---------------------------------------------------------------- K1: per-joint LN + attention-pool scores
__global__ __launch_bounds__(64) void ln1_scores(const float* __restrict__ x,
                                                 const float* __restrict__ g,
                                                 const float* __restrict__ bta,
                                                 const float* __restrict__ apw,
                                                 const float* __restrict__ apb,
                                                 float* __restrict__ xr,
                                                 float* __restrict__ scores) {
  int bn = blockIdx.x, lane = threadIdx.x;
  int f = lane & 31, half = lane >> 5;
  const float* row = x + (size_t)bn * CC;
  float gg = g[f], bb = bta[f], aw = apw[f], ab = apb[0];
  for (int it = 0; it < 9; ++it) {
    int j = it * 2 + half;
    bool act = (j < JJ);
    float v = act ? row[j * FF + f] : 0.f;
    float s = v;
    for (int m = 16; m >= 1; m >>= 1) s += __shfl_xor(s, m);
    float mu = s * (1.f / 32.f);
    float dv = v - mu;
    float s2 = dv * dv;
    for (int m = 16; m >= 1; m >>= 1) s2 += __shfl_xor(s2, m);
    float xn = dv * rsqrtf(s2 * (1.f / 32.f) + 1e-5f) * gg + bb;
    float sc = xn * aw;
    for (int m = 16; m >= 1; m >>= 1) sc += __shfl_xor(sc, m);
    if (act) {
      xr[(size_t)bn * CC + j * FF + f] = xn;
      if (f == 0) scores[bn * JJ + j] = sc + ab;
    }
  }
}

// ---------------------------------------------------------------- K2: softmax over sequence axis N per (b,j)
__global__ __launch_bounds__(256) void softmax_n(const float* __restrict__ scores,
                                                 float* __restrict__ wsm) {
  int bj = blockIdx.x;
  int b = bj / JJ, j = bj - b * JJ;
  const float* s = scores + (size_t)b * NN * JJ + j;
  float* wp = wsm + (size_t)b * NN * JJ + j;
  int t = threadIdx.x;
  float v[4];
  float mx = -1e30f;
#pragma unroll
  for (int i = 0; i < 4; ++i) { v[i] = s[(t + 256 * i) * JJ]; mx = fmaxf(mx, v[i]); }
#pragma unroll
  for (int m = 32; m >= 1; m >>= 1) mx = fmaxf(mx, __shfl_xor(mx, m));
  __shared__ float red[4];
  if ((t & 63) == 0) red[t >> 6] = mx;
  __syncthreads();
  mx = fmaxf(fmaxf(red[0], red[1]), fmaxf(red[2], red[3]));
  float sum = 0.f;
#pragma unroll
  for (int i = 0; i < 4; ++i) { v[i] = __expf(v[i] - mx); sum += v[i]; }
#pragma unroll
  for (int m = 32; m >= 1; m >>= 1) sum += __shfl_xor(sum, m);
  __shared__ float red2[4];
  if ((t & 63) == 0) red2[t >> 6] = sum;
  __syncthreads();
  sum = red2[0] + red2[1] + red2[2] + red2[3];
  float inv = 1.f / sum;
#pragma unroll
  for (int i = 0; i < 4; ++i) wp[(t + 256 * i) * JJ] = v[i] * inv;
}

// ---------------------------------------------------------------- K3: xp = xr*w, LN2 over C, -> bf16
__global__ __launch_bounds__(64) void ln2_xp(const float* __restrict__ xr,
                                             const float* __restrict__ wsm,
                                             const float* __restrict__ g2,
                                             const float* __restrict__ b2,
                                             __hip_bfloat16* __restrict__ xp) {
  int bn = blockIdx.x, lane = threadIdx.x;
  __shared__ float wsh[JJ];
  if (lane < JJ) wsh[lane] = wsm[bn * JJ + lane];
  __syncthreads();
  float vals[9];
  float sum = 0.f;
  for (int it = 0; it < 9; ++it) {
    int c = it * 64 + lane;
    float v = 0.f;
    if (c < CC) v = xr[(size_t)bn * CC + c] * wsh[c >> 5];
    vals[it] = v;
    sum += v;
  }
  for (int m = 32; m >= 1; m >>= 1) sum += __shfl_xor(sum, m);
  float mu = sum * (1.f / 544.f);
  float s2 = 0.f;
  for (int it = 0; it < 9; ++it) {
    int c = it * 64 + lane;
    if (c < CC) { float dv = vals[it] - mu; s2 += dv * dv; }
  }
  for (int m = 32; m >= 1; m >>= 1) s2 += __shfl_xor(s2, m);
  float rstd = rsqrtf(s2 * (1.f / 544.f) + 1e-5f);
  for (int it = 0; it < 9; ++it) {
    int c = it * 64 + lane;
    if (c < CC)
      xp[(size_t)bn * CC + c] = __float2bfloat16((vals[it] - mu) * rstd * g2[c] + b2[c]);
  }
}

// ---------------------------------------------------------------- GEMM: C[M,N] = A[M,K] * B[N,K]^T, bf16 MFMA
// XCD-swizzled 1-D grid + double-buffered single-barrier K-loop (R10, kept).
template <int MODE>
__global__ __launch_bounds__(256) void gemm_nt(const __hip_bfloat16* __restrict__ A,
                                               const __hip_bfloat16* __restrict__ Bw,
                                               __hip_bfloat16* __restrict__ Qp,
                                               __hip_bfloat16* __restrict__ Kp,
                                               __hip_bfloat16* __restrict__ Vt,
                                               float* __restrict__ Cf,
                                               const float* __restrict__ bias,
                                               const float* __restrict__ sfp) {
  __shared__ __hip_bfloat16 As[2][128 * 32];
  __shared__ __hip_bfloat16 Bs[2][128 * 32];
  const int t = threadIdx.x;
  const int w = t >> 6, lane = t & 63;
  const int fr = lane & 15, fq = lane >> 4;
  const int bi = blockIdx.x;
  const int xcd = bi & 7, j = bi >> 3;
  const int bx = xcd * 8 + (j & 7), by = j >> 3;
  const int m0 = bx * 128;
  const int n0 = by * 128;
  const int wm = (w >> 1) * 64, wn = (w & 1) * 64;

  f32x4 acc[4][4] = {};

  const __hip_bfloat16* Ag = A + (size_t)m0 * KD;
  const __hip_bfloat16* Bg = Bw + (size_t)n0 * KD;

#pragma unroll
  for (int i2 = 0; i2 < 2; ++i2) {
    int cb = (i2 * 4 + w) * 64;
    int chunk = cb + lane;
    int row = chunk >> 2, c16 = chunk & 3;
    gld_lds16(Ag + (size_t)row * KD + c16 * 8, &As[0][cb * 8]);
    gld_lds16(Bg + (size_t)row * KD + c16 * 8, &Bs[0][cb * 8]);
  }
  __syncthreads();

  for (int kt = 0; kt < 17; ++kt) {
    const int cur = kt & 1;
    if (kt < 16) {
      const int k0 = (kt + 1) * 32;
#pragma unroll
      for (int i2 = 0; i2 < 2; ++i2) {
        int cb = (i2 * 4 + w) * 64;
        int chunk = cb + lane;
        int row = chunk >> 2, c16 = chunk & 3;
        gld_lds16(Ag + (size_t)row * KD + k0 + c16 * 8, &As[1 - cur][cb * 8]);
        gld_lds16(Bg + (size_t)row * KD + k0 + c16 * 8, &Bs[1 - cur][cb * 8]);
      }
    }
    bf16x8 af[4], bfr[4];
#pragma unroll
    for (int tm = 0; tm < 4; ++tm)
      af[tm] = *(const bf16x8*)&As[cur][(wm + tm * 16 + fr) * 32 + fq * 8];
#pragma unroll
    for (int tn = 0; tn < 4; ++tn)
      bfr[tn] = *(const bf16x8*)&Bs[cur][(wn + tn * 16 + fr) * 32 + fq * 8];
#pragma unroll
    for (int tm = 0; tm < 4; ++tm)
#pragma unroll
      for (int tn = 0; tn < 4; ++tn)
        acc[tm][tn] = __builtin_amdgcn_mfma_f32_16x16x32_bf16(af[tm], bfr[tn], acc[tm][tn], 0, 0, 0);
    __syncthreads();  // cur reads done; drains kt+1 prefetch (hidden behind MFMAs)
  }

  if (MODE == 1) {
#pragma unroll
    for (int tn = 0; tn < 4; ++tn) {
      int o = n0 + wn + tn * 16 + fr;
      if (o < CC) {
        float bb = bias[o];
#pragma unroll
        for (int tm = 0; tm < 4; ++tm) {
          int m = m0 + wm + tm * 16 + fq * 4;
#pragma unroll
          for (int r = 0; r < 4; ++r)
            Cf[(size_t)(m + r) * CC + o] = acc[tm][tn][r] + bb;
        }
      }
    }
  } else {
    int b = m0 >> 10;
    float sf = sfp[0];
#pragma unroll
    for (int tn = 0; tn < 4; ++tn) {
      int o = n0 + wn + tn * 16 + fr;
      if (o < 2 * CC) {  // q or k -> head-major padded
        bool is_k = (o >= CC);
        int oo = is_k ? o - CC : o;
        int h = oo / HD;
        int d = oo - h * HD;
        __hip_bfloat16* base = is_k ? Kp : Qp;
        __hip_bfloat16* dst = base + ((size_t)(b * HH + h) * NN) * HDP + d;
#pragma unroll
        for (int tm = 0; tm < 4; ++tm) {
          int m = m0 + wm + tm * 16 + fq * 4;
          int n = m & (NN - 1);
#pragma unroll
          for (int r = 0; r < 4; ++r) {
            float v = acc[tm][tn][r];
            if (is_k) {
              // fold softmax scale * per-key positional scale into K
              float pos = (n + r) * (1.f / 1023.f) - 0.5f;
              v *= __expf(-sf * pos * pos) * 0.12126781251816650f;  // 68^-0.5
            }
            dst[(size_t)(n + r) * HDP] = __float2bfloat16(v);
          }
        }
      } else if (o < NCQ) {  // v -> transposed
        int oo = o - 2 * CC;
        int h = oo / HD;
        int d = oo - h * HD;
        __hip_bfloat16* vrow = Vt + (((size_t)b * HH + h) * HD + d) * NN;
#pragma unroll
        for (int tm = 0; tm < 4; ++tm) {
          int m = m0 + wm + tm * 16 + fq * 4;
          int n = m & (NN - 1);
#pragma unroll
          for (int r = 0; r < 4; ++r)
            vrow[n + r] = __float2bfloat16(acc[tm][tn][r]);
        }
      }
    }
  }
}

// ---------------------------------------------------------------- Flash attention v3: ZERO-barrier, all-register
// 128-thread blocks (2 waves x 2 row-groups x 16 = 64 q-rows), grid 1024 with
// idx = bh + 64*qt swizzle (XCD L2 reuse). Q fragments loaded once from global;
// K and V fragments loaded per-tile straight into registers (L2-resident,
// B-fragment rows are 16B-contiguous in the padded layouts). LDS only for the
// per-wave-group P round-trip (same-wave write->read, lgkmcnt only) -> NO
// __syncthreads anywhere; waves free-run their 16 tiles.
// No-max softmax (logits pre-scaled via K fold, ~N(0,1)); l reduced once at end.
__global__ __launch_bounds__(128) void attn_kernel(const __hip_bfloat16* __restrict__ Qp,
                                                   const __hip_bfloat16* __restrict__ Kp,
                                                   const __hip_bfloat16* __restrict__ Vt,
                                                   __hip_bfloat16* __restrict__ Ao) {
  __shared__ __hip_bfloat16 Ps[4 * 16 * 72];  // 9216B, one 16x72 region per wave-group
  const int t = threadIdx.x;
  const int w = t >> 6, lane = t & 63;
  const int fr = lane & 15, fq = lane >> 4;
  const int idx = blockIdx.x;
  const int bh = idx & 63, qt = idx >> 6;
  const int h = bh & 7, b = bh >> 3;

  const __hip_bfloat16* qtile = Qp + ((size_t)bh * NN + qt * AQR) * HDP;
  const __hip_bfloat16* kbase = Kp + (size_t)bh * NN * HDP;
  const __hip_bfloat16* vbase = Vt + (size_t)bh * HD * NN;

  // ---- Q fragments straight from global (once)
  bf16x8 qa[2][3];
#pragma unroll
  for (int g = 0; g < 2; ++g)
#pragma unroll
    for (int ks = 0; ks < 3; ++ks)
      qa[g][ks] = *(const bf16x8*)(qtile + (size_t)(w * 32 + g * 16 + fr) * HDP + ks * 32 + fq * 8);

  f32x4 o_acc[2][5] = {};
  float l_part[2][4] = {};
  const int dclamp = (fr < 4) ? 0 : 1;  // tv=4 rows 64+fr valid only for fr<4

  for (int kt = 0; kt < 16; ++kt) {
    // ---- K(kt) fragments -> registers (12 x 16B contiguous loads)
    bf16x8 kfr[4][3];
#pragma unroll
    for (int tn = 0; tn < 4; ++tn)
#pragma unroll
      for (int ks = 0; ks < 3; ++ks)
        kfr[tn][ks] = *(const bf16x8*)(kbase + (size_t)(kt * 64 + tn * 16 + fr) * HDP + ks * 32 + fq * 8);
    // ---- V(kt) fragments -> registers (used ~300cyc later in PV; latency hidden)
    bf16x8 vfrag[5][2];
#pragma unroll
    for (int tv = 0; tv < 5; ++tv) {
      int d = tv * 16 + fr;
      int dc = (tv == 4 && dclamp) ? 0 : d;  // clamp OOB rows; outputs discarded
#pragma unroll
      for (int ks2 = 0; ks2 < 2; ++ks2)
        vfrag[tv][ks2] = *(const bf16x8*)(vbase + (size_t)dc * NN + kt * 64 + ks2 * 32 + fq * 8);
    }

    // ---- S = Q K^T for both row-groups; each K fragment feeds 2 MFMAs
    f32x4 s[2][4] = {};
#pragma unroll
    for (int tn = 0; tn < 4; ++tn) {
#pragma unroll
      for (int ks = 0; ks < 3; ++ks) {
        s[0][tn] = __builtin_amdgcn_mfma_f32_16x16x32_bf16(qa[0][ks], kfr[tn][ks], s[0][tn], 0, 0, 0);
        s[1][tn] = __builtin_amdgcn_mfma_f32_16x16x32_bf16(qa[1][ks], kfr[tn][ks], s[1][tn], 0, 0, 0);
      }
    }
    // ---- no-max softmax: p = exp(s); per-lane partial row sums
#pragma unroll
    for (int g = 0; g < 2; ++g) {
      __hip_bfloat16* Pw = &Ps[(w * 2 + g) * 1152];  // 16x72 per-wave-group region
#pragma unroll
      for (int tn = 0; tn < 4; ++tn)
#pragma unroll
        for (int r = 0; r < 4; ++r) {
          float p = __expf(s[g][tn][r]);
          l_part[g][r] += p;
          Pw[(fq * 4 + r) * 72 + tn * 16 + fr] = __float2bfloat16(p);
        }
    }
    // ---- O += P V; same-wave LDS round-trip (lgkmcnt only, no barrier)
#pragma unroll
    for (int ks2 = 0; ks2 < 2; ++ks2) {
      bf16x8 pa0 = *(const bf16x8*)&Ps[(w * 2 + 0) * 1152 + fr * 72 + ks2 * 32 + fq * 8];
      bf16x8 pa1 = *(const bf16x8*)&Ps[(w * 2 + 1) * 1152 + fr * 72 + ks2 * 32 + fq * 8];
#pragma unroll
      for (int tv = 0; tv < 5; ++tv) {
        o_acc[0][tv] = __builtin_amdgcn_mfma_f32_16x16x32_bf16(pa0, vfrag[tv][ks2], o_acc[0][tv], 0, 0, 0);
        o_acc[1][tv] = __builtin_amdgcn_mfma_f32_16x16x32_bf16(pa1, vfrag[tv][ks2], o_acc[1][tv], 0, 0, 0);
      }
    }
  }
  // ---- epilogue: reduce l across the 16 row-lanes (4 shfls, once), O / l -> bf16
#pragma unroll
  for (int g = 0; g < 2; ++g) {
    __hip_bfloat16* obase = Ao + (size_t)(b * NN + qt * AQR + w * 32 + g * 16) * CC + h * HD;
    float inv[4];
#pragma unroll
    for (int r = 0; r < 4; ++r) {
      float l = l_part[g][r];
#pragma unroll
      for (int msk = 8; msk >= 1; msk >>= 1) l += __shfl_xor(l, msk);
      inv[r] = 1.f / l;
    }
#pragma unroll
    for (int tv = 0; tv < 5; ++tv) {
      int d = tv * 16 + fr;
      if (d < HD) {
#pragma unroll
        for (int r = 0; r < 4; ++r)
          obase[(size_t)(fq * 4 + r) * CC + d] = __float2bfloat16(o_acc[g][tv][r] * inv[r]);
      }
    }
  }
}

// ---------------------------------------------------------------- launch
extern "C" void kernel_launch(void* const* d_in, const int* in_sizes, int n_in,
                              void* d_out, int out_size, void* d_ws, size_t ws_size,
                              hipStream_t stream) {
  (void)in_sizes; (void)n_in; (void)out_size; (void)ws_size;
  const float* x       = (const float*)d_in[0];
  const float* norm_g  = (const float*)d_in[1];
  const float* norm_b  = (const float*)d_in[2];
  const float* ap_w    = (const float*)d_in[3];
  const float* ap_b    = (const float*)d_in[4];
  const float* norm2_g = (const float*)d_in[5];
  const float* norm2_b = (const float*)d_in[6];
  const float* qkv_w   = (const float*)d_in[7];
  const float* proj_w  = (const float*)d_in[8];
  const float* proj_b  = (const float*)d_in[9];
  const float* sf      = (const float*)d_in[10];
  float* out = (float*)d_out;
  char* ws = (char*)d_ws;

  // workspace layout (bytes)
  float* xr              = (float*)(ws);                       // 8192*544*4  = 17825792
  float* scores          = (float*)(ws + 17825792);            // 8192*17*4   = 557056
  float* wsm             = (float*)(ws + 18382848);            // 557056
  __hip_bfloat16* xp     = (__hip_bfloat16*)(ws + 18939904);   // 8192*544*2  = 8912896
  __hip_bfloat16* qw     = (__hip_bfloat16*)(ws + 27852800);   // 1664*544*2  = 1810432
  __hip_bfloat16* pw     = (__hip_bfloat16*)(ws + 29663232);   // 640*544*2   = 696320
  __hip_bfloat16* vt     = (__hip_bfloat16*)(ws + 30359552);   // 8*8*68*1024*2 = 8912896
  __hip_bfloat16* ao     = (__hip_bfloat16*)(ws + 39272448);   // 8192*544*2  = 8912896
  __hip_bfloat16* qp     = (__hip_bfloat16*)(ws + 48185344);   // 8*8*1024*96*2 = 12582912
  __hip_bfloat16* kp     = (__hip_bfloat16*)(ws + 60768256);   // 12582912
  // total 73351168 bytes

  wconv<<<8480, 256, 0, stream>>>(qkv_w, proj_w, qw, pw, (char*)qp);
  ln1_scores<<<BN, 64, 0, stream>>>(x, norm_g, norm_b, ap_w, ap_b, xr, scores);
  softmax_n<<<BB * JJ, 256, 0, stream>>>(scores, wsm);
  ln2_xp<<<BN, 64, 0, stream>>>(xr, wsm, norm2_g, norm2_b, xp);
  gemm_nt<0><<<dim3(64 * 13), 256, 0, stream>>>(xp, qw, qp, kp, vt, nullptr, nullptr, sf);
  attn_kernel<<<dim3((NN / AQR) * HH * BB), 128, 0, stream>>>(qp, kp, vt, ao);
  gemm_nt<1><<<dim3(64 * 5), 256, 0, stream>>>(ao, pw, nullptr, nullptr, nullptr, out, proj_b, nullptr);
}

// Round 12
// 227.998 us; speedup vs baseline: 1.0659x; 1.0659x over previous
//
#include <hip/hip_runtime.h>
#include <hip/hip_bf16.h>

// Problem constants
#define BB 8
#define NN 1024
#define CC 544      // J*F = 17*32
#define JJ 17
#define FF 32
#define HH 8
#define HD 68
#define BN 8192     // B*N
#define KD 544      // GEMM K dim (=C)
#define NCQ 1632    // 3*C
#define NCQP 1664   // padded to 13*128
#define NCPP 640    // proj out padded to 5*128
#define HDP 96      // head dim padded for QK (3x K=32)
#define AQR 64      // q-rows per attention block (2 waves x 2 groups x 16)

using f32x4  = __attribute__((ext_vector_type(4))) float;
using bf16x8 = __attribute__((ext_vector_type(8))) short;

__device__ __forceinline__ void gld_lds16(const void* g, void* l) {
  __builtin_amdgcn_global_load_lds(
      (const __attribute__((address_space(1))) void*)g,
      (__attribute__((address_space(3))) void*)l, 16, 0, 0);
}

// ---------------------------------------------------------------- K0: weights -> bf16 (padded) + zero Qp/Kp pad cols
__global__ __launch_bounds__(256) void wconv(const float* __restrict__ qkv_w,
                                             const float* __restrict__ proj_w,
                                             __hip_bfloat16* __restrict__ qw,
                                             __hip_bfloat16* __restrict__ pw,
                                             char* __restrict__ qkp) {
  int idx = blockIdx.x * 256 + threadIdx.x;
  const int t1 = NCQP * KD;            // 905216
  const int t2 = t1 + NCPP * KD;       // 1253376
  if (idx < t1) {
    int r = idx / KD;
    qw[idx] = __float2bfloat16(r < NCQ ? qkv_w[idx] : 0.f);
  } else if (idx < t2) {
    int k = idx - t1;
    int r = k / KD;
    pw[k] = __float2bfloat16(r < CC ? proj_w[k] : 0.f);
  } else {
    // zero pad cols 68..95 of Qp||Kp: 131072 rows x 7 qwords (56B at byte 136)
    int k = idx - t2;
    if (k < 131072 * 7) {
      int row = k / 7, i = k - row * 7;
      *(unsigned long long*)(qkp + (size_t)row * 192 + 136 + i * 8) = 0ull;
    }
  }
}

// ---------------------------------------------------------------- K1: per-joint LN + attention-pool scores (xr -> bf16)
__global__ __launch_bounds__(64) void ln1_scores(const float* __restrict__ x,
                                                 const float* __restrict__ g,
                                                 const float* __restrict__ bta,
                                                 const float* __restrict__ apw,
                                                 const float* __restrict__ apb,
                                                 __hip_bfloat16* __restrict__ xr,
                                                 float* __restrict__ scores) {
  int bn = blockIdx.x, lane = threadIdx.x;
  int f = lane & 31, half = lane >> 5;
  const float* row = x + (size_t)bn * CC;
  float gg = g[f], bb = bta[f], aw = apw[f], ab = apb[0];
  for (int it = 0; it < 9; ++it) {
    int j = it * 2 + half;
    bool act = (j < JJ);
    float v = act ? row[j * FF + f] : 0.f;
    float s = v;
    for (int m = 16; m >= 1; m >>= 1) s += __shfl_xor(s, m);
    float mu = s * (1.f / 32.f);
    float dv = v - mu;
    float s2 = dv * dv;
    for (int m = 16; m >= 1; m >>= 1) s2 += __shfl_xor(s2, m);
    float xn = dv * rsqrtf(s2 * (1.f / 32.f) + 1e-5f) * gg + bb;
    float sc = xn * aw;
    for (int m = 16; m >= 1; m >>= 1) sc += __shfl_xor(sc, m);
    if (act) {
      xr[(size_t)bn * CC + j * FF + f] = __float2bfloat16(xn);
      if (f == 0) scores[bn * JJ + j] = sc + ab;
    }
  }
}

// ---------------------------------------------------------------- K2: per-(b,j) softmax stats over N -> {max, 1/sum}
__global__ __launch_bounds__(256) void softmax_red(const float* __restrict__ scores,
                                                   float2* __restrict__ tab) {
  int bj = blockIdx.x;
  int b = bj / JJ, j = bj - b * JJ;
  const float* s = scores + (size_t)b * NN * JJ + j;
  int t = threadIdx.x;
  float v[4];
  float mx = -1e30f;
#pragma unroll
  for (int i = 0; i < 4; ++i) { v[i] = s[(t + 256 * i) * JJ]; mx = fmaxf(mx, v[i]); }
#pragma unroll
  for (int m = 32; m >= 1; m >>= 1) mx = fmaxf(mx, __shfl_xor(mx, m));
  __shared__ float red[4];
  if ((t & 63) == 0) red[t >> 6] = mx;
  __syncthreads();
  mx = fmaxf(fmaxf(red[0], red[1]), fmaxf(red[2], red[3]));
  float sum = 0.f;
#pragma unroll
  for (int i = 0; i < 4; ++i) sum += __expf(v[i] - mx);
#pragma unroll
  for (int m = 32; m >= 1; m >>= 1) sum += __shfl_xor(sum, m);
  __shared__ float red2[4];
  if ((t & 63) == 0) red2[t >> 6] = sum;
  __syncthreads();
  if (t == 0) {
    sum = red2[0] + red2[1] + red2[2] + red2[3];
    tab[bj] = make_float2(mx, 1.f / sum);
  }
}

// ---------------------------------------------------------------- K3: xp = xr*w (w recomputed from scores+tab), LN2, -> bf16
__global__ __launch_bounds__(64) void ln2_xp(const __hip_bfloat16* __restrict__ xr,
                                             const float* __restrict__ scores,
                                             const float2* __restrict__ tab,
                                             const float* __restrict__ g2,
                                             const float* __restrict__ b2,
                                             __hip_bfloat16* __restrict__ xp) {
  int bn = blockIdx.x, lane = threadIdx.x;
  __shared__ float wsh[JJ];
  if (lane < JJ) {
    float sc = scores[bn * JJ + lane];
    float2 mi = tab[(bn >> 10) * JJ + lane];
    wsh[lane] = __expf(sc - mi.x) * mi.y;
  }
  __syncthreads();
  float vals[9];
  float sum = 0.f;
  for (int it = 0; it < 9; ++it) {
    int c = it * 64 + lane;
    float v = 0.f;
    if (c < CC) v = __bfloat162float(xr[(size_t)bn * CC + c]) * wsh[c >> 5];
    vals[it] = v;
    sum += v;
  }
  for (int m = 32; m >= 1; m >>= 1) sum += __shfl_xor(sum, m);
  float mu = sum * (1.f / 544.f);
  float s2 = 0.f;
  for (int it = 0; it < 9; ++it) {
    int c = it * 64 + lane;
    if (c < CC) { float dv = vals[it] - mu; s2 += dv * dv; }
  }
  for (int m = 32; m >= 1; m >>= 1) s2 += __shfl_xor(s2, m);
  float rstd = rsqrtf(s2 * (1.f / 544.f) + 1e-5f);
  for (int it = 0; it < 9; ++it) {
    int c = it * 64 + lane;
    if (c < CC)
      xp[(size_t)bn * CC + c] = __float2bfloat16((vals[it] - mu) * rstd * g2[c] + b2[c]);
  }
}

// ---------------------------------------------------------------- GEMM: C[M,N] = A[M,K] * B[N,K]^T, bf16 MFMA
// XCD-swizzled 1-D grid + double-buffered single-barrier K-loop (R10, kept).
template <int MODE>
__global__ __launch_bounds__(256) void gemm_nt(const __hip_bfloat16* __restrict__ A,
                                               const __hip_bfloat16* __restrict__ Bw,
                                               __hip_bfloat16* __restrict__ Qp,
                                               __hip_bfloat16* __restrict__ Kp,
                                               __hip_bfloat16* __restrict__ Vt,
                                               float* __restrict__ Cf,
                                               const float* __restrict__ bias,
                                               const float* __restrict__ sfp) {
  __shared__ __hip_bfloat16 As[2][128 * 32];
  __shared__ __hip_bfloat16 Bs[2][128 * 32];
  const int t = threadIdx.x;
  const int w = t >> 6, lane = t & 63;
  const int fr = lane & 15, fq = lane >> 4;
  const int bi = blockIdx.x;
  const int xcd = bi & 7, j = bi >> 3;
  const int bx = xcd * 8 + (j & 7), by = j >> 3;
  const int m0 = bx * 128;
  const int n0 = by * 128;
  const int wm = (w >> 1) * 64, wn = (w & 1) * 64;

  f32x4 acc[4][4] = {};

  const __hip_bfloat16* Ag = A + (size_t)m0 * KD;
  const __hip_bfloat16* Bg = Bw + (size_t)n0 * KD;

#pragma unroll
  for (int i2 = 0; i2 < 2; ++i2) {
    int cb = (i2 * 4 + w) * 64;
    int chunk = cb + lane;
    int row = chunk >> 2, c16 = chunk & 3;
    gld_lds16(Ag + (size_t)row * KD + c16 * 8, &As[0][cb * 8]);
    gld_lds16(Bg + (size_t)row * KD + c16 * 8, &Bs[0][cb * 8]);
  }
  __syncthreads();

  for (int kt = 0; kt < 17; ++kt) {
    const int cur = kt & 1;
    if (kt < 16) {
      const int k0 = (kt + 1) * 32;
#pragma unroll
      for (int i2 = 0; i2 < 2; ++i2) {
        int cb = (i2 * 4 + w) * 64;
        int chunk = cb + lane;
        int row = chunk >> 2, c16 = chunk & 3;
        gld_lds16(Ag + (size_t)row * KD + k0 + c16 * 8, &As[1 - cur][cb * 8]);
        gld_lds16(Bg + (size_t)row * KD + k0 + c16 * 8, &Bs[1 - cur][cb * 8]);
      }
    }
    bf16x8 af[4], bfr[4];
#pragma unroll
    for (int tm = 0; tm < 4; ++tm)
      af[tm] = *(const bf16x8*)&As[cur][(wm + tm * 16 + fr) * 32 + fq * 8];
#pragma unroll
    for (int tn = 0; tn < 4; ++tn)
      bfr[tn] = *(const bf16x8*)&Bs[cur][(wn + tn * 16 + fr) * 32 + fq * 8];
#pragma unroll
    for (int tm = 0; tm < 4; ++tm)
#pragma unroll
      for (int tn = 0; tn < 4; ++tn)
        acc[tm][tn] = __builtin_amdgcn_mfma_f32_16x16x32_bf16(af[tm], bfr[tn], acc[tm][tn], 0, 0, 0);
    __syncthreads();  // cur reads done; drains kt+1 prefetch (hidden behind MFMAs)
  }

  if (MODE == 1) {
#pragma unroll
    for (int tn = 0; tn < 4; ++tn) {
      int o = n0 + wn + tn * 16 + fr;
      if (o < CC) {
        float bb = bias[o];
#pragma unroll
        for (int tm = 0; tm < 4; ++tm) {
          int m = m0 + wm + tm * 16 + fq * 4;
#pragma unroll
          for (int r = 0; r < 4; ++r)
            Cf[(size_t)(m + r) * CC + o] = acc[tm][tn][r] + bb;
        }
      }
    }
  } else {
    int b = m0 >> 10;
    float sf = sfp[0];
#pragma unroll
    for (int tn = 0; tn < 4; ++tn) {
      int o = n0 + wn + tn * 16 + fr;
      if (o < 2 * CC) {  // q or k -> head-major padded
        bool is_k = (o >= CC);
        int oo = is_k ? o - CC : o;
        int h = oo / HD;
        int d = oo - h * HD;
        __hip_bfloat16* base = is_k ? Kp : Qp;
        __hip_bfloat16* dst = base + ((size_t)(b * HH + h) * NN) * HDP + d;
#pragma unroll
        for (int tm = 0; tm < 4; ++tm) {
          int m = m0 + wm + tm * 16 + fq * 4;
          int n = m & (NN - 1);
#pragma unroll
          for (int r = 0; r < 4; ++r) {
            float v = acc[tm][tn][r];
            if (is_k) {
              // fold softmax scale * per-key positional scale into K
              float pos = (n + r) * (1.f / 1023.f) - 0.5f;
              v *= __expf(-sf * pos * pos) * 0.12126781251816650f;  // 68^-0.5
            }
            dst[(size_t)(n + r) * HDP] = __float2bfloat16(v);
          }
        }
      } else if (o < NCQ) {  // v -> transposed
        int oo = o - 2 * CC;
        int h = oo / HD;
        int d = oo - h * HD;
        __hip_bfloat16* vrow = Vt + (((size_t)b * HH + h) * HD + d) * NN;
#pragma unroll
        for (int tm = 0; tm < 4; ++tm) {
          int m = m0 + wm + tm * 16 + fq * 4;
          int n = m & (NN - 1);
#pragma unroll
          for (int r = 0; r < 4; ++r)
            vrow[n + r] = __float2bfloat16(acc[tm][tn][r]);
        }
      }
    }
  }
}

// ---------------------------------------------------------------- Flash attention (R8 winner, reverted verbatim)
// 128-thread blocks (2 waves x 2 row-groups x 16 = 64 q-rows), grid 1024 with
// idx = bh + 64*qt swizzle (XCD L2 reuse). Single barrier per K-tile:
// K LDS double-buffered, K(kt+1) DMA issued at tile top, drained by the
// END-of-tile barrier. V straight to registers. No-max softmax (logits
// pre-scaled via K fold); l reduced once in the epilogue.
// R9 post-mortem: 256-thr/launch_bounds(256,4) made the compiler sink V loads
// (VGPR 60, serial chain) -> 86us. R11 post-mortem: all-register K (no LDS
// share) -> 69us. Keep THIS shape (VGPR 124).
__global__ __launch_bounds__(128) void attn_kernel(const __hip_bfloat16* __restrict__ Qp,
                                                   const __hip_bfloat16* __restrict__ Kp,
                                                   const __hip_bfloat16* __restrict__ Vt,
                                                   __hip_bfloat16* __restrict__ Ao) {
  __shared__ __hip_bfloat16 Qs[12 * 64 * 8];     // 12288B; reused as Ps[4][16][72] after prologue
  __shared__ __hip_bfloat16 Ks[2][12 * 64 * 8];  // 2 x 12288B double buffer
  const int t = threadIdx.x;
  const int w = t >> 6, lane = t & 63;
  const int fr = lane & 15, fq = lane >> 4;
  const int idx = blockIdx.x;
  const int bh = idx & 63, qt = idx >> 6;
  const int h = bh & 7, b = bh >> 3;

  const __hip_bfloat16* qtile = Qp + ((size_t)bh * NN + qt * AQR) * HDP;
  const __hip_bfloat16* kbase = Kp + (size_t)bh * NN * HDP;
  const __hip_bfloat16* vbase = Vt + (size_t)bh * HD * NN;

  // ---- prologue: Q + K0 via DMA, k-major: LDS slot (kblk*64 + row), row = lane
#pragma unroll
  for (int i = 0; i < 6; ++i) {
    int kb = i * 2 + w;  // wave-uniform kblk
    gld_lds16(qtile + (size_t)lane * HDP + kb * 8, &Qs[kb * 64 * 8]);
  }
#pragma unroll
  for (int i = 0; i < 6; ++i) {
    int kb = i * 2 + w;
    gld_lds16(kbase + (size_t)lane * HDP + kb * 8, &Ks[0][kb * 64 * 8]);
  }
  __syncthreads();  // drain Q + K0 DMA
  bf16x8 qa[2][3];
#pragma unroll
  for (int g = 0; g < 2; ++g)
#pragma unroll
    for (int ks = 0; ks < 3; ++ks)
      qa[g][ks] = *(const bf16x8*)&Qs[((ks * 4 + fq) * 64 + w * 32 + g * 16 + fr) * 8];
  __syncthreads();  // all waves done reading Qs before it becomes Ps scratch

  f32x4 o_acc[2][5] = {};
  float l_part[2][4] = {};
  const int dclamp = (fr < 4) ? 0 : 1;  // tv=4 rows 64+fr valid only for fr<4

  for (int kt = 0; kt < 16; ++kt) {
    const int cur = kt & 1;
    // ---- V(kt) -> registers (issued first so the vfrag waitcnt leaves K DMA in flight)
    bf16x8 vfrag[5][2];
#pragma unroll
    for (int tv = 0; tv < 5; ++tv) {
      int d = tv * 16 + fr;
      int dc = (tv == 4 && dclamp) ? 0 : d;  // clamp OOB rows; outputs discarded
#pragma unroll
      for (int ks2 = 0; ks2 < 2; ++ks2)
        vfrag[tv][ks2] = *(const bf16x8*)(vbase + (size_t)dc * NN + kt * 64 + ks2 * 32 + fq * 8);
    }
    // ---- K(kt+1) DMA into the other buffer; drained at the END-of-tile barrier
    if (kt < 15) {
      const __hip_bfloat16* ktile = kbase + (size_t)(kt + 1) * 64 * HDP;
#pragma unroll
      for (int i = 0; i < 6; ++i) {
        int kb = i * 2 + w;
        gld_lds16(ktile + (size_t)lane * HDP + kb * 8, &Ks[1 - cur][kb * 64 * 8]);
      }
    }

    // ---- S = Q K^T for both row-groups; each K fragment load feeds 2 MFMAs
    f32x4 s[2][4] = {};
#pragma unroll
    for (int tn = 0; tn < 4; ++tn) {
#pragma unroll
      for (int ks = 0; ks < 3; ++ks) {
        bf16x8 kb = *(const bf16x8*)&Ks[cur][((ks * 4 + fq) * 64 + tn * 16 + fr) * 8];
        s[0][tn] = __builtin_amdgcn_mfma_f32_16x16x32_bf16(qa[0][ks], kb, s[0][tn], 0, 0, 0);
        s[1][tn] = __builtin_amdgcn_mfma_f32_16x16x32_bf16(qa[1][ks], kb, s[1][tn], 0, 0, 0);
      }
    }
    // ---- no-max softmax: p = exp(s); per-lane partial row sums (reduced once at end)
#pragma unroll
    for (int g = 0; g < 2; ++g) {
      __hip_bfloat16* Pw = &Qs[(w * 2 + g) * 1152];  // 16x72 per-wave-group region
#pragma unroll
      for (int tn = 0; tn < 4; ++tn)
#pragma unroll
        for (int r = 0; r < 4; ++r) {
          float p = __expf(s[g][tn][r]);
          l_part[g][r] += p;
          Pw[(fq * 4 + r) * 72 + tn * 16 + fr] = __float2bfloat16(p);
        }
    }
    // ---- O += P V; V fragments from registers
#pragma unroll
    for (int ks2 = 0; ks2 < 2; ++ks2) {
      bf16x8 pa0 = *(const bf16x8*)&Qs[(w * 2 + 0) * 1152 + fr * 72 + ks2 * 32 + fq * 8];
      bf16x8 pa1 = *(const bf16x8*)&Qs[(w * 2 + 1) * 1152 + fr * 72 + ks2 * 32 + fq * 8];
#pragma unroll
      for (int tv = 0; tv < 5; ++tv) {
        o_acc[0][tv] = __builtin_amdgcn_mfma_f32_16x16x32_bf16(pa0, vfrag[tv][ks2], o_acc[0][tv], 0, 0, 0);
        o_acc[1][tv] = __builtin_amdgcn_mfma_f32_16x16x32_bf16(pa1, vfrag[tv][ks2], o_acc[1][tv], 0, 0, 0);
      }
    }
    __syncthreads();  // end of tile: Ks[cur]/Ps reads done; drains kt+1 prefetch (hidden)
  }
  // ---- epilogue: reduce l across the 16 row-lanes (4 shfls, once), O / l -> bf16
#pragma unroll
  for (int g = 0; g < 2; ++g) {
    __hip_bfloat16* obase = Ao + (size_t)(b * NN + qt * AQR + w * 32 + g * 16) * CC + h * HD;
    float inv[4];
#pragma unroll
    for (int r = 0; r < 4; ++r) {
      float l = l_part[g][r];
#pragma unroll
      for (int msk = 8; msk >= 1; msk >>= 1) l += __shfl_xor(l, msk);
      inv[r] = 1.f / l;
    }
#pragma unroll
    for (int tv = 0; tv < 5; ++tv) {
      int d = tv * 16 + fr;
      if (d < HD) {
#pragma unroll
        for (int r = 0; r < 4; ++r)
          obase[(size_t)(fq * 4 + r) * CC + d] = __float2bfloat16(o_acc[g][tv][r] * inv[r]);
      }
    }
  }
}

// ---------------------------------------------------------------- launch
extern "C" void kernel_launch(void* const* d_in, const int* in_sizes, int n_in,
                              void* d_out, int out_size, void* d_ws, size_t ws_size,
                              hipStream_t stream) {
  (void)in_sizes; (void)n_in; (void)out_size; (void)ws_size;
  const float* x       = (const float*)d_in[0];
  const float* norm_g  = (const float*)d_in[1];
  const float* norm_b  = (const float*)d_in[2];
  const float* ap_w    = (const float*)d_in[3];
  const float* ap_b    = (const float*)d_in[4];
  const float* norm2_g = (const float*)d_in[5];
  const float* norm2_b = (const float*)d_in[6];
  const float* qkv_w   = (const float*)d_in[7];
  const float* proj_w  = (const float*)d_in[8];
  const float* proj_b  = (const float*)d_in[9];
  const float* sf      = (const float*)d_in[10];
  float* out = (float*)d_out;
  char* ws = (char*)d_ws;

  // workspace layout (bytes) — compacted, 63.9MB total
  __hip_bfloat16* xr   = (__hip_bfloat16*)(ws);                // 8192*544*2  = 8912896
  float* scores        = (float*)(ws + 8912896);               // 8192*17*4   = 557056
  float2* tab          = (float2*)(ws + 9469952);              // 136*8 -> pad 4096
  __hip_bfloat16* xp   = (__hip_bfloat16*)(ws + 9474048);      // 8912896
  __hip_bfloat16* qw   = (__hip_bfloat16*)(ws + 18386944);     // 1664*544*2  = 1810432
  __hip_bfloat16* pw   = (__hip_bfloat16*)(ws + 20197376);     // 640*544*2   = 696320
  __hip_bfloat16* vt   = (__hip_bfloat16*)(ws + 20893696);     // 8*8*68*1024*2 = 8912896
  __hip_bfloat16* ao   = (__hip_bfloat16*)(ws + 29806592);     // 8912896
  __hip_bfloat16* qp   = (__hip_bfloat16*)(ws + 38719488);     // 8*8*1024*96*2 = 12582912
  __hip_bfloat16* kp   = (__hip_bfloat16*)(ws + 51302400);     // 12582912
  // total 63885312 bytes

  wconv<<<8480, 256, 0, stream>>>(qkv_w, proj_w, qw, pw, (char*)qp);
  ln1_scores<<<BN, 64, 0, stream>>>(x, norm_g, norm_b, ap_w, ap_b, xr, scores);
  softmax_red<<<BB * JJ, 256, 0, stream>>>(scores, tab);
  ln2_xp<<<BN, 64, 0, stream>>>(xr, scores, tab, norm2_g, norm2_b, xp);
  gemm_nt<0><<<dim3(64 * 13), 256, 0, stream>>>(xp, qw, qp, kp, vt, nullptr, nullptr, sf);
  attn_kernel<<<dim3((NN / AQR) * HH * BB), 128, 0, stream>>>(qp, kp, vt, ao);
  gemm_nt<1><<<dim3(64 * 5), 256, 0, stream>>>(ao, pw, nullptr, nullptr, nullptr, out, proj_b, nullptr);
}

// Round 13
// 223.712 us; speedup vs baseline: 1.0863x; 1.0192x over previous
//
#include <hip/hip_runtime.h>
#include <hip/hip_bf16.h>

// Problem constants
#define BB 8
#define NN 1024
#define CC 544      // J*F = 17*32
#define JJ 17
#define FF 32
#define HH 8
#define HD 68
#define BN 8192     // B*N
#define KD 544      // GEMM K dim (=C)
#define NCQ 1632    // 3*C
#define NCQP 1664   // padded to 13*128
#define NCPP 640    // proj out padded to 5*128
#define HDP 96      // head dim padded for QK (3x K=32)
#define AQR 64      // q-rows per attention block (2 waves x 2 groups x 16)

using f32x4  = __attribute__((ext_vector_type(4))) float;
using bf16x8 = __attribute__((ext_vector_type(8))) short;

__device__ __forceinline__ void gld_lds16(const void* g, void* l) {
  __builtin_amdgcn_global_load_lds(
      (const __attribute__((address_space(1))) void*)g,
      (__attribute__((address_space(3))) void*)l, 16, 0, 0);
}

// ---------------------------------------------------------------- K0: weights -> bf16 (padded) + zero Qp/Kp pad cols
// One block per weight row: float4 coalesced loads, packed 8B bf16 stores, no divisions.
// Blocks >= NCQP+NCPP: one thread zeroes one Qp/Kp row's 56B pad.
__global__ __launch_bounds__(256) void wconv(const float* __restrict__ qkv_w,
                                             const float* __restrict__ proj_w,
                                             __hip_bfloat16* __restrict__ qw,
                                             __hip_bfloat16* __restrict__ pw,
                                             char* __restrict__ qkp) {
  int bid = blockIdx.x, t = threadIdx.x;
  if (bid < NCQP + NCPP) {
    bool isq = bid < NCQP;
    int r = isq ? bid : bid - NCQP;
    const float* src = isq ? qkv_w : proj_w;
    __hip_bfloat16* dst = isq ? qw : pw;
    int nrows = isq ? NCQ : CC;
    if (t < KD / 4) {
      int c = t * 4;
      float4 v;
      if (r < nrows) v = *(const float4*)(src + (size_t)r * KD + c);
      else           v = float4{0.f, 0.f, 0.f, 0.f};
      __hip_bfloat16 o[4] = {__float2bfloat16(v.x), __float2bfloat16(v.y),
                             __float2bfloat16(v.z), __float2bfloat16(v.w)};
      *(unsigned long long*)(dst + (size_t)r * KD + c) = *(unsigned long long*)o;
    }
  } else {
    int row = (bid - (NCQP + NCPP)) * 256 + t;  // 131072 rows (Qp||Kp)
    if (row < 131072) {
      char* p = qkp + (size_t)row * 192 + 136;
#pragma unroll
      for (int i = 0; i < 7; ++i) *(unsigned long long*)(p + i * 8) = 0ull;
    }
  }
}

// ---------------------------------------------------------------- K1: per-joint LN + attention-pool scores (xr -> bf16)
// 256-thread blocks = 4 waves = 4 tokens; per-wave logic unchanged.
__global__ __launch_bounds__(256) void ln1_scores(const float* __restrict__ x,
                                                  const float* __restrict__ g,
                                                  const float* __restrict__ bta,
                                                  const float* __restrict__ apw,
                                                  const float* __restrict__ apb,
                                                  __hip_bfloat16* __restrict__ xr,
                                                  float* __restrict__ scores) {
  int wv = threadIdx.x >> 6, lane = threadIdx.x & 63;
  int bn = blockIdx.x * 4 + wv;
  int f = lane & 31, half = lane >> 5;
  const float* row = x + (size_t)bn * CC;
  float gg = g[f], bb = bta[f], aw = apw[f], ab = apb[0];
  for (int it = 0; it < 9; ++it) {
    int j = it * 2 + half;
    bool act = (j < JJ);
    float v = act ? row[j * FF + f] : 0.f;
    float s = v;
    for (int m = 16; m >= 1; m >>= 1) s += __shfl_xor(s, m);
    float mu = s * (1.f / 32.f);
    float dv = v - mu;
    float s2 = dv * dv;
    for (int m = 16; m >= 1; m >>= 1) s2 += __shfl_xor(s2, m);
    float xn = dv * rsqrtf(s2 * (1.f / 32.f) + 1e-5f) * gg + bb;
    float sc = xn * aw;
    for (int m = 16; m >= 1; m >>= 1) sc += __shfl_xor(sc, m);
    if (act) {
      xr[(size_t)bn * CC + j * FF + f] = __float2bfloat16(xn);
      if (f == 0) scores[bn * JJ + j] = sc + ab;
    }
  }
}

// ---------------------------------------------------------------- K2: per-(b,j) softmax stats over N -> {max, 1/sum}
__global__ __launch_bounds__(256) void softmax_red(const float* __restrict__ scores,
                                                   float2* __restrict__ tab) {
  int bj = blockIdx.x;
  int b = bj / JJ, j = bj - b * JJ;
  const float* s = scores + (size_t)b * NN * JJ + j;
  int t = threadIdx.x;
  float v[4];
  float mx = -1e30f;
#pragma unroll
  for (int i = 0; i < 4; ++i) { v[i] = s[(t + 256 * i) * JJ]; mx = fmaxf(mx, v[i]); }
#pragma unroll
  for (int m = 32; m >= 1; m >>= 1) mx = fmaxf(mx, __shfl_xor(mx, m));
  __shared__ float red[4];
  if ((t & 63) == 0) red[t >> 6] = mx;
  __syncthreads();
  mx = fmaxf(fmaxf(red[0], red[1]), fmaxf(red[2], red[3]));
  float sum = 0.f;
#pragma unroll
  for (int i = 0; i < 4; ++i) sum += __expf(v[i] - mx);
#pragma unroll
  for (int m = 32; m >= 1; m >>= 1) sum += __shfl_xor(sum, m);
  __shared__ float red2[4];
  if ((t & 63) == 0) red2[t >> 6] = sum;
  __syncthreads();
  if (t == 0) {
    sum = red2[0] + red2[1] + red2[2] + red2[3];
    tab[bj] = make_float2(mx, 1.f / sum);
  }
}

// ---------------------------------------------------------------- K3: xp = xr*w (w recomputed from scores+tab), LN2, -> bf16
// 256-thread blocks = 4 waves = 4 tokens; per-wave wsh (same-wave LDS round-trip, no barrier).
__global__ __launch_bounds__(256) void ln2_xp(const __hip_bfloat16* __restrict__ xr,
                                              const float* __restrict__ scores,
                                              const float2* __restrict__ tab,
                                              const float* __restrict__ g2,
                                              const float* __restrict__ b2,
                                              __hip_bfloat16* __restrict__ xp) {
  __shared__ float wsh[4][JJ];
  int wv = threadIdx.x >> 6, lane = threadIdx.x & 63;
  int bn = blockIdx.x * 4 + wv;
  if (lane < JJ) {
    float sc = scores[bn * JJ + lane];
    float2 mi = tab[(bn >> 10) * JJ + lane];
    wsh[wv][lane] = __expf(sc - mi.x) * mi.y;
  }
  // same-wave producer/consumer: lgkmcnt ordering suffices, no __syncthreads
  float vals[9];
  float sum = 0.f;
  for (int it = 0; it < 9; ++it) {
    int c = it * 64 + lane;
    float v = 0.f;
    if (c < CC) v = __bfloat162float(xr[(size_t)bn * CC + c]) * wsh[wv][c >> 5];
    vals[it] = v;
    sum += v;
  }
  for (int m = 32; m >= 1; m >>= 1) sum += __shfl_xor(sum, m);
  float mu = sum * (1.f / 544.f);
  float s2 = 0.f;
  for (int it = 0; it < 9; ++it) {
    int c = it * 64 + lane;
    if (c < CC) { float dv = vals[it] - mu; s2 += dv * dv; }
  }
  for (int m = 32; m >= 1; m >>= 1) s2 += __shfl_xor(s2, m);
  float rstd = rsqrtf(s2 * (1.f / 544.f) + 1e-5f);
  for (int it = 0; it < 9; ++it) {
    int c = it * 64 + lane;
    if (c < CC)
      xp[(size_t)bn * CC + c] = __float2bfloat16((vals[it] - mu) * rstd * g2[c] + b2[c]);
  }
}

// ---------------------------------------------------------------- GEMM: C[M,N] = A[M,K] * B[N,K]^T, bf16 MFMA
// XCD-swizzled 1-D grid + double-buffered single-barrier K-loop (R10, kept).
template <int MODE>
__global__ __launch_bounds__(256) void gemm_nt(const __hip_bfloat16* __restrict__ A,
                                               const __hip_bfloat16* __restrict__ Bw,
                                               __hip_bfloat16* __restrict__ Qp,
                                               __hip_bfloat16* __restrict__ Kp,
                                               __hip_bfloat16* __restrict__ Vt,
                                               float* __restrict__ Cf,
                                               const float* __restrict__ bias,
                                               const float* __restrict__ sfp) {
  __shared__ __hip_bfloat16 As[2][128 * 32];
  __shared__ __hip_bfloat16 Bs[2][128 * 32];
  const int t = threadIdx.x;
  const int w = t >> 6, lane = t & 63;
  const int fr = lane & 15, fq = lane >> 4;
  const int bi = blockIdx.x;
  const int xcd = bi & 7, j = bi >> 3;
  const int bx = xcd * 8 + (j & 7), by = j >> 3;
  const int m0 = bx * 128;
  const int n0 = by * 128;
  const int wm = (w >> 1) * 64, wn = (w & 1) * 64;

  f32x4 acc[4][4] = {};

  const __hip_bfloat16* Ag = A + (size_t)m0 * KD;
  const __hip_bfloat16* Bg = Bw + (size_t)n0 * KD;

#pragma unroll
  for (int i2 = 0; i2 < 2; ++i2) {
    int cb = (i2 * 4 + w) * 64;
    int chunk = cb + lane;
    int row = chunk >> 2, c16 = chunk & 3;
    gld_lds16(Ag + (size_t)row * KD + c16 * 8, &As[0][cb * 8]);
    gld_lds16(Bg + (size_t)row * KD + c16 * 8, &Bs[0][cb * 8]);
  }
  __syncthreads();

  for (int kt = 0; kt < 17; ++kt) {
    const int cur = kt & 1;
    if (kt < 16) {
      const int k0 = (kt + 1) * 32;
#pragma unroll
      for (int i2 = 0; i2 < 2; ++i2) {
        int cb = (i2 * 4 + w) * 64;
        int chunk = cb + lane;
        int row = chunk >> 2, c16 = chunk & 3;
        gld_lds16(Ag + (size_t)row * KD + k0 + c16 * 8, &As[1 - cur][cb * 8]);
        gld_lds16(Bg + (size_t)row * KD + k0 + c16 * 8, &Bs[1 - cur][cb * 8]);
      }
    }
    bf16x8 af[4], bfr[4];
#pragma unroll
    for (int tm = 0; tm < 4; ++tm)
      af[tm] = *(const bf16x8*)&As[cur][(wm + tm * 16 + fr) * 32 + fq * 8];
#pragma unroll
    for (int tn = 0; tn < 4; ++tn)
      bfr[tn] = *(const bf16x8*)&Bs[cur][(wn + tn * 16 + fr) * 32 + fq * 8];
#pragma unroll
    for (int tm = 0; tm < 4; ++tm)
#pragma unroll
      for (int tn = 0; tn < 4; ++tn)
        acc[tm][tn] = __builtin_amdgcn_mfma_f32_16x16x32_bf16(af[tm], bfr[tn], acc[tm][tn], 0, 0, 0);
    __syncthreads();  // cur reads done; drains kt+1 prefetch (hidden behind MFMAs)
  }

  if (MODE == 1) {
#pragma unroll
    for (int tn = 0; tn < 4; ++tn) {
      int o = n0 + wn + tn * 16 + fr;
      if (o < CC) {
        float bb = bias[o];
#pragma unroll
        for (int tm = 0; tm < 4; ++tm) {
          int m = m0 + wm + tm * 16 + fq * 4;
#pragma unroll
          for (int r = 0; r < 4; ++r)
            Cf[(size_t)(m + r) * CC + o] = acc[tm][tn][r] + bb;
        }
      }
    }
  } else {
    int b = m0 >> 10;
    float sf = sfp[0];
#pragma unroll
    for (int tn = 0; tn < 4; ++tn) {
      int o = n0 + wn + tn * 16 + fr;
      if (o < 2 * CC) {  // q or k -> head-major padded
        bool is_k = (o >= CC);
        int oo = is_k ? o - CC : o;
        int h = oo / HD;
        int d = oo - h * HD;
        __hip_bfloat16* base = is_k ? Kp : Qp;
        __hip_bfloat16* dst = base + ((size_t)(b * HH + h) * NN) * HDP + d;
#pragma unroll
        for (int tm = 0; tm < 4; ++tm) {
          int m = m0 + wm + tm * 16 + fq * 4;
          int n = m & (NN - 1);
#pragma unroll
          for (int r = 0; r < 4; ++r) {
            float v = acc[tm][tn][r];
            if (is_k) {
              // fold softmax scale * per-key positional scale into K
              float pos = (n + r) * (1.f / 1023.f) - 0.5f;
              v *= __expf(-sf * pos * pos) * 0.12126781251816650f;  // 68^-0.5
            }
            dst[(size_t)(n + r) * HDP] = __float2bfloat16(v);
          }
        }
      } else if (o < NCQ) {  // v -> transposed
        int oo = o - 2 * CC;
        int h = oo / HD;
        int d = oo - h * HD;
        __hip_bfloat16* vrow = Vt + (((size_t)b * HH + h) * HD + d) * NN;
#pragma unroll
        for (int tm = 0; tm < 4; ++tm) {
          int m = m0 + wm + tm * 16 + fq * 4;
          int n = m & (NN - 1);
#pragma unroll
          for (int r = 0; r < 4; ++r)
            vrow[n + r] = __float2bfloat16(acc[tm][tn][r]);
        }
      }
    }
  }
}

// ---------------------------------------------------------------- Flash attention (R8 winner, frozen)
// 128-thread blocks (2 waves x 2 row-groups x 16 = 64 q-rows), grid 1024 with
// idx = bh + 64*qt swizzle (XCD L2 reuse). Single barrier per K-tile:
// K LDS double-buffered, K(kt+1) DMA issued at tile top, drained by the
// END-of-tile barrier. V straight to registers. No-max softmax (logits
// pre-scaled via K fold); l reduced once in the epilogue.
// R9: 256-thr/lb(256,4) sank V loads (VGPR 60) -> 86us. R11: all-register K
// -> 69us. This shape (VGPR 124) is the measured plateau ~64-66us.
__global__ __launch_bounds__(128) void attn_kernel(const __hip_bfloat16* __restrict__ Qp,
                                                   const __hip_bfloat16* __restrict__ Kp,
                                                   const __hip_bfloat16* __restrict__ Vt,
                                                   __hip_bfloat16* __restrict__ Ao) {
  __shared__ __hip_bfloat16 Qs[12 * 64 * 8];     // 12288B; reused as Ps[4][16][72] after prologue
  __shared__ __hip_bfloat16 Ks[2][12 * 64 * 8];  // 2 x 12288B double buffer
  const int t = threadIdx.x;
  const int w = t >> 6, lane = t & 63;
  const int fr = lane & 15, fq = lane >> 4;
  const int idx = blockIdx.x;
  const int bh = idx & 63, qt = idx >> 6;
  const int h = bh & 7, b = bh >> 3;

  const __hip_bfloat16* qtile = Qp + ((size_t)bh * NN + qt * AQR) * HDP;
  const __hip_bfloat16* kbase = Kp + (size_t)bh * NN * HDP;
  const __hip_bfloat16* vbase = Vt + (size_t)bh * HD * NN;

  // ---- prologue: Q + K0 via DMA, k-major: LDS slot (kblk*64 + row), row = lane
#pragma unroll
  for (int i = 0; i < 6; ++i) {
    int kb = i * 2 + w;  // wave-uniform kblk
    gld_lds16(qtile + (size_t)lane * HDP + kb * 8, &Qs[kb * 64 * 8]);
  }
#pragma unroll
  for (int i = 0; i < 6; ++i) {
    int kb = i * 2 + w;
    gld_lds16(kbase + (size_t)lane * HDP + kb * 8, &Ks[0][kb * 64 * 8]);
  }
  __syncthreads();  // drain Q + K0 DMA
  bf16x8 qa[2][3];
#pragma unroll
  for (int g = 0; g < 2; ++g)
#pragma unroll
    for (int ks = 0; ks < 3; ++ks)
      qa[g][ks] = *(const bf16x8*)&Qs[((ks * 4 + fq) * 64 + w * 32 + g * 16 + fr) * 8];
  __syncthreads();  // all waves done reading Qs before it becomes Ps scratch

  f32x4 o_acc[2][5] = {};
  float l_part[2][4] = {};
  const int dclamp = (fr < 4) ? 0 : 1;  // tv=4 rows 64+fr valid only for fr<4

  for (int kt = 0; kt < 16; ++kt) {
    const int cur = kt & 1;
    // ---- V(kt) -> registers (issued first so the vfrag waitcnt leaves K DMA in flight)
    bf16x8 vfrag[5][2];
#pragma unroll
    for (int tv = 0; tv < 5; ++tv) {
      int d = tv * 16 + fr;
      int dc = (tv == 4 && dclamp) ? 0 : d;  // clamp OOB rows; outputs discarded
#pragma unroll
      for (int ks2 = 0; ks2 < 2; ++ks2)
        vfrag[tv][ks2] = *(const bf16x8*)(vbase + (size_t)dc * NN + kt * 64 + ks2 * 32 + fq * 8);
    }
    // ---- K(kt+1) DMA into the other buffer; drained at the END-of-tile barrier
    if (kt < 15) {
      const __hip_bfloat16* ktile = kbase + (size_t)(kt + 1) * 64 * HDP;
#pragma unroll
      for (int i = 0; i < 6; ++i) {
        int kb = i * 2 + w;
        gld_lds16(ktile + (size_t)lane * HDP + kb * 8, &Ks[1 - cur][kb * 64 * 8]);
      }
    }

    // ---- S = Q K^T for both row-groups; each K fragment load feeds 2 MFMAs
    f32x4 s[2][4] = {};
#pragma unroll
    for (int tn = 0; tn < 4; ++tn) {
#pragma unroll
      for (int ks = 0; ks < 3; ++ks) {
        bf16x8 kb = *(const bf16x8*)&Ks[cur][((ks * 4 + fq) * 64 + tn * 16 + fr) * 8];
        s[0][tn] = __builtin_amdgcn_mfma_f32_16x16x32_bf16(qa[0][ks], kb, s[0][tn], 0, 0, 0);
        s[1][tn] = __builtin_amdgcn_mfma_f32_16x16x32_bf16(qa[1][ks], kb, s[1][tn], 0, 0, 0);
      }
    }
    // ---- no-max softmax: p = exp(s); per-lane partial row sums (reduced once at end)
#pragma unroll
    for (int g = 0; g < 2; ++g) {
      __hip_bfloat16* Pw = &Qs[(w * 2 + g) * 1152];  // 16x72 per-wave-group region
#pragma unroll
      for (int tn = 0; tn < 4; ++tn)
#pragma unroll
        for (int r = 0; r < 4; ++r) {
          float p = __expf(s[g][tn][r]);
          l_part[g][r] += p;
          Pw[(fq * 4 + r) * 72 + tn * 16 + fr] = __float2bfloat16(p);
        }
    }
    // ---- O += P V; V fragments from registers
#pragma unroll
    for (int ks2 = 0; ks2 < 2; ++ks2) {
      bf16x8 pa0 = *(const bf16x8*)&Qs[(w * 2 + 0) * 1152 + fr * 72 + ks2 * 32 + fq * 8];
      bf16x8 pa1 = *(const bf16x8*)&Qs[(w * 2 + 1) * 1152 + fr * 72 + ks2 * 32 + fq * 8];
#pragma unroll
      for (int tv = 0; tv < 5; ++tv) {
        o_acc[0][tv] = __builtin_amdgcn_mfma_f32_16x16x32_bf16(pa0, vfrag[tv][ks2], o_acc[0][tv], 0, 0, 0);
        o_acc[1][tv] = __builtin_amdgcn_mfma_f32_16x16x32_bf16(pa1, vfrag[tv][ks2], o_acc[1][tv], 0, 0, 0);
      }
    }
    __syncthreads();  // end of tile: Ks[cur]/Ps reads done; drains kt+1 prefetch (hidden)
  }
  // ---- epilogue: reduce l across the 16 row-lanes (4 shfls, once), O / l -> bf16
#pragma unroll
  for (int g = 0; g < 2; ++g) {
    __hip_bfloat16* obase = Ao + (size_t)(b * NN + qt * AQR + w * 32 + g * 16) * CC + h * HD;
    float inv[4];
#pragma unroll
    for (int r = 0; r < 4; ++r) {
      float l = l_part[g][r];
#pragma unroll
      for (int msk = 8; msk >= 1; msk >>= 1) l += __shfl_xor(l, msk);
      inv[r] = 1.f / l;
    }
#pragma unroll
    for (int tv = 0; tv < 5; ++tv) {
      int d = tv * 16 + fr;
      if (d < HD) {
#pragma unroll
        for (int r = 0; r < 4; ++r)
          obase[(size_t)(fq * 4 + r) * CC + d] = __float2bfloat16(o_acc[g][tv][r] * inv[r]);
      }
    }
  }
}

// ---------------------------------------------------------------- launch
extern "C" void kernel_launch(void* const* d_in, const int* in_sizes, int n_in,
                              void* d_out, int out_size, void* d_ws, size_t ws_size,
                              hipStream_t stream) {
  (void)in_sizes; (void)n_in; (void)out_size; (void)ws_size;
  const float* x       = (const float*)d_in[0];
  const float* norm_g  = (const float*)d_in[1];
  const float* norm_b  = (const float*)d_in[2];
  const float* ap_w    = (const float*)d_in[3];
  const float* ap_b    = (const float*)d_in[4];
  const float* norm2_g = (const float*)d_in[5];
  const float* norm2_b = (const float*)d_in[6];
  const float* qkv_w   = (const float*)d_in[7];
  const float* proj_w  = (const float*)d_in[8];
  const float* proj_b  = (const float*)d_in[9];
  const float* sf      = (const float*)d_in[10];
  float* out = (float*)d_out;
  char* ws = (char*)d_ws;

  // workspace layout (bytes) — compacted, 63.9MB total
  __hip_bfloat16* xr   = (__hip_bfloat16*)(ws);                // 8192*544*2  = 8912896
  float* scores        = (float*)(ws + 8912896);               // 8192*17*4   = 557056
  float2* tab          = (float2*)(ws + 9469952);              // 136*8 -> pad 4096
  __hip_bfloat16* xp   = (__hip_bfloat16*)(ws + 9474048);      // 8912896
  __hip_bfloat16* qw   = (__hip_bfloat16*)(ws + 18386944);     // 1664*544*2  = 1810432
  __hip_bfloat16* pw   = (__hip_bfloat16*)(ws + 20197376);     // 640*544*2   = 696320
  __hip_bfloat16* vt   = (__hip_bfloat16*)(ws + 20893696);     // 8*8*68*1024*2 = 8912896
  __hip_bfloat16* ao   = (__hip_bfloat16*)(ws + 29806592);     // 8912896
  __hip_bfloat16* qp   = (__hip_bfloat16*)(ws + 38719488);     // 8*8*1024*96*2 = 12582912
  __hip_bfloat16* kp   = (__hip_bfloat16*)(ws + 51302400);     // 12582912
  // total 63885312 bytes

  wconv<<<NCQP + NCPP + 512, 256, 0, stream>>>(qkv_w, proj_w, qw, pw, (char*)qp);
  ln1_scores<<<BN / 4, 256, 0, stream>>>(x, norm_g, norm_b, ap_w, ap_b, xr, scores);
  softmax_red<<<BB * JJ, 256, 0, stream>>>(scores, tab);
  ln2_xp<<<BN / 4, 256, 0, stream>>>(xr, scores, tab, norm2_g, norm2_b, xp);
  gemm_nt<0><<<dim3(64 * 13), 256, 0, stream>>>(xp, qw, qp, kp, vt, nullptr, nullptr, sf);
  attn_kernel<<<dim3((NN / AQR) * HH * BB), 128, 0, stream>>>(qp, kp, vt, ao);
  gemm_nt<1><<<dim3(64 * 5), 256, 0, stream>>>(ao, pw, nullptr, nullptr, nullptr, out, proj_b, nullptr);
}